// Round 1
// baseline (2357.211 us; speedup 1.0000x reference)
//
#include <hip/hip_runtime.h>
#include <hip/hip_bf16.h>

#define T_SEQ 512
#define BATCH 16
#define EMB 768
#define HEADS 32
#define HDIM 24
#define ROWS (T_SEQ * BATCH)  /* 8192 */
#define SCALING 0.20412414523193154f /* 24^-0.5 */

// ---------------------------------------------------------------------------
// Fused QKV projection: X[8192,768] @ W^T + b for W in {Wq,Wk,Wv}.
// Output layout [bh = b*32+h][t][dd] so attention reads are contiguous.
// Tile: 64x64, BK=16, 256 threads, 4x4 micro-tile per thread.
// ---------------------------------------------------------------------------
__global__ __launch_bounds__(256)
void qkv_proj_kernel(const float* __restrict__ X,
                     const float* __restrict__ Wq, const float* __restrict__ Wk,
                     const float* __restrict__ Wv,
                     const float* __restrict__ bq, const float* __restrict__ bk,
                     const float* __restrict__ bv,
                     float* __restrict__ qo, float* __restrict__ ko,
                     float* __restrict__ vo)
{
    __shared__ float Xs[64][17];                       // +1 pad: break 4-way bank alias
    __shared__ __attribute__((aligned(16))) float Ws[16][68]; // stride 68: float4-aligned, 2-way only

    const int tid = threadIdx.x;
    const int r0 = blockIdx.x * 64;
    const int nb = blockIdx.y;            // 0..35 -> (q|k|v) x 12 col-blocks
    const int which = nb / 12;
    const int n0 = (nb % 12) * 64;
    const float* W    = (which == 0) ? Wq : (which == 1) ? Wk : Wv;
    const float* bias = (which == 0) ? bq : (which == 1) ? bk : bv;
    float* out        = (which == 0) ? qo : (which == 1) ? ko : vo;

    const int lrow = tid >> 2;            // 0..63
    const int lcol = (tid & 3) << 2;      // 0,4,8,12
    const int tx = tid & 15;
    const int ty = tid >> 4;

    float acc[4][4] = {};

    for (int k0 = 0; k0 < EMB; k0 += 16) {
        const float4 xv = *(const float4*)(X + (size_t)(r0 + lrow) * EMB + k0 + lcol);
        const float4 wv = *(const float4*)(W + (size_t)(n0 + lrow) * EMB + k0 + lcol);
        Xs[lrow][lcol + 0] = xv.x; Xs[lrow][lcol + 1] = xv.y;
        Xs[lrow][lcol + 2] = xv.z; Xs[lrow][lcol + 3] = xv.w;
        Ws[lcol + 0][lrow] = wv.x; Ws[lcol + 1][lrow] = wv.y;
        Ws[lcol + 2][lrow] = wv.z; Ws[lcol + 3][lrow] = wv.w;
        __syncthreads();
#pragma unroll
        for (int kk = 0; kk < 16; ++kk) {
            const float4 b4 = *(const float4*)&Ws[kk][tx * 4];
            const float a0 = Xs[ty * 4 + 0][kk];
            const float a1 = Xs[ty * 4 + 1][kk];
            const float a2 = Xs[ty * 4 + 2][kk];
            const float a3 = Xs[ty * 4 + 3][kk];
            acc[0][0] += a0 * b4.x; acc[0][1] += a0 * b4.y; acc[0][2] += a0 * b4.z; acc[0][3] += a0 * b4.w;
            acc[1][0] += a1 * b4.x; acc[1][1] += a1 * b4.y; acc[1][2] += a1 * b4.z; acc[1][3] += a1 * b4.w;
            acc[2][0] += a2 * b4.x; acc[2][1] += a2 * b4.y; acc[2][2] += a2 * b4.z; acc[2][3] += a2 * b4.w;
            acc[3][0] += a3 * b4.x; acc[3][1] += a3 * b4.y; acc[3][2] += a3 * b4.z; acc[3][3] += a3 * b4.w;
        }
        __syncthreads();
    }

#pragma unroll
    for (int ii = 0; ii < 4; ++ii) {
        const int rr = r0 + ty * 4 + ii;
        const int t = rr >> 4;
        const int b = rr & 15;
#pragma unroll
        for (int jj = 0; jj < 4; ++jj) {
            const int nn = n0 + tx * 4 + jj;
            float c = acc[ii][jj] + bias[nn];
            if (which == 0) c *= SCALING;
            const int h = nn / HDIM;
            const int dd = nn - h * HDIM;
            out[((size_t)((b * HEADS + h) * T_SEQ + t)) * HDIM + dd] = c;
        }
    }
}

// ---------------------------------------------------------------------------
// Attention: one block per (bh, 16 query rows). Scores (16x512) in LDS,
// two-pass softmax, then PV. Bias streamed coalesced (the 512 MB read).
// ---------------------------------------------------------------------------
__global__ __launch_bounds__(256)
void attn_kernel(const float* __restrict__ qb, const float* __restrict__ kb,
                 const float* __restrict__ vb, const float* __restrict__ bias,
                 float* __restrict__ attn)
{
    const int bh = blockIdx.x;            // 0..511  (= b*32 + h)
    const int t0 = blockIdx.y * 16;
    const int tid = threadIdx.x;

    __shared__ float Qs[16][25];
    __shared__ float Ss[16][513];         // 513: i-dependent bank rotation
    __shared__ float red[16][17];
    __shared__ float rowm[16];
    __shared__ float rowl[16];

    const float* Kb = kb + (size_t)bh * T_SEQ * HDIM;
    const float* Vb = vb + (size_t)bh * T_SEQ * HDIM;
    const float* Bb = bias + (size_t)bh * T_SEQ * T_SEQ + (size_t)t0 * T_SEQ;

    for (int e = tid; e < 16 * HDIM; e += 256) {
        const int i = e / HDIM, dd = e - i * HDIM;
        Qs[i][dd] = qb[((size_t)bh * T_SEQ + t0 + i) * HDIM + dd];
    }
    __syncthreads();

    // scores = (scaled q) . k + bias
    for (int e = tid; e < 16 * T_SEQ; e += 256) {
        const int i = e >> 9, s = e & 511;
        const float* kr = Kb + s * HDIM;
        float d = 0.f;
#pragma unroll
        for (int dd = 0; dd < HDIM; ++dd) d += Qs[i][dd] * kr[dd];
        Ss[i][s] = d + Bb[i * T_SEQ + s];
    }
    __syncthreads();

    // softmax per row (16 threads per row)
    const int i = tid >> 4;
    const int g = tid & 15;
    float m = -1e30f;
    for (int s = g; s < T_SEQ; s += 16) m = fmaxf(m, Ss[i][s]);
    red[i][g] = m;
    __syncthreads();
    if (g == 0) {
        float mm = red[i][0];
#pragma unroll
        for (int j = 1; j < 16; ++j) mm = fmaxf(mm, red[i][j]);
        rowm[i] = mm;
    }
    __syncthreads();
    const float mrow = rowm[i];
    float l = 0.f;
    for (int s = g; s < T_SEQ; s += 16) {
        const float p = __expf(Ss[i][s] - mrow);
        Ss[i][s] = p;
        l += p;
    }
    red[i][g] = l;
    __syncthreads();
    if (g == 0) {
        float ll = 0.f;
#pragma unroll
        for (int j = 0; j < 16; ++j) ll += red[i][j];
        rowl[i] = 1.f / ll;
    }
    __syncthreads();

    // PV: out[i][dd] = (1/l) * sum_s P[i][s] * V[s][dd]
    for (int p = tid; p < 16 * HDIM; p += 256) {
        const int ii = p / HDIM, dd = p - ii * HDIM;
        float accv = 0.f;
        const float* vp = Vb + dd;
#pragma unroll 8
        for (int s = 0; s < T_SEQ; ++s) accv += Ss[ii][s] * vp[s * HDIM];
        accv *= rowl[ii];
        const int t = t0 + ii;
        const int b = bh >> 5;
        const int h = bh & 31;
        attn[((size_t)(t * BATCH + b)) * EMB + h * HDIM + dd] = accv;
    }
}

// ---------------------------------------------------------------------------
// Output projection: attn[8192,768] @ Wo^T + bo -> out (same tile as qkv)
// ---------------------------------------------------------------------------
__global__ __launch_bounds__(256)
void out_proj_kernel(const float* __restrict__ A, const float* __restrict__ Wo,
                     const float* __restrict__ bo, float* __restrict__ out)
{
    __shared__ float Xs[64][17];
    __shared__ __attribute__((aligned(16))) float Ws[16][68];

    const int tid = threadIdx.x;
    const int r0 = blockIdx.x * 64;
    const int n0 = blockIdx.y * 64;

    const int lrow = tid >> 2;
    const int lcol = (tid & 3) << 2;
    const int tx = tid & 15;
    const int ty = tid >> 4;

    float acc[4][4] = {};

    for (int k0 = 0; k0 < EMB; k0 += 16) {
        const float4 xv = *(const float4*)(A + (size_t)(r0 + lrow) * EMB + k0 + lcol);
        const float4 wv = *(const float4*)(Wo + (size_t)(n0 + lrow) * EMB + k0 + lcol);
        Xs[lrow][lcol + 0] = xv.x; Xs[lrow][lcol + 1] = xv.y;
        Xs[lrow][lcol + 2] = xv.z; Xs[lrow][lcol + 3] = xv.w;
        Ws[lcol + 0][lrow] = wv.x; Ws[lcol + 1][lrow] = wv.y;
        Ws[lcol + 2][lrow] = wv.z; Ws[lcol + 3][lrow] = wv.w;
        __syncthreads();
#pragma unroll
        for (int kk = 0; kk < 16; ++kk) {
            const float4 b4 = *(const float4*)&Ws[kk][tx * 4];
            const float a0 = Xs[ty * 4 + 0][kk];
            const float a1 = Xs[ty * 4 + 1][kk];
            const float a2 = Xs[ty * 4 + 2][kk];
            const float a3 = Xs[ty * 4 + 3][kk];
            acc[0][0] += a0 * b4.x; acc[0][1] += a0 * b4.y; acc[0][2] += a0 * b4.z; acc[0][3] += a0 * b4.w;
            acc[1][0] += a1 * b4.x; acc[1][1] += a1 * b4.y; acc[1][2] += a1 * b4.z; acc[1][3] += a1 * b4.w;
            acc[2][0] += a2 * b4.x; acc[2][1] += a2 * b4.y; acc[2][2] += a2 * b4.z; acc[2][3] += a2 * b4.w;
            acc[3][0] += a3 * b4.x; acc[3][1] += a3 * b4.y; acc[3][2] += a3 * b4.z; acc[3][3] += a3 * b4.w;
        }
        __syncthreads();
    }

#pragma unroll
    for (int ii = 0; ii < 4; ++ii) {
        const int rr = r0 + ty * 4 + ii;
#pragma unroll
        for (int jj = 0; jj < 4; ++jj) {
            const int nn = n0 + tx * 4 + jj;
            out[(size_t)rr * EMB + nn] = acc[ii][jj] + bo[nn];
        }
    }
}

extern "C" void kernel_launch(void* const* d_in, const int* in_sizes, int n_in,
                              void* d_out, int out_size, void* d_ws, size_t ws_size,
                              hipStream_t stream)
{
    const float* query = (const float*)d_in[0];   // [512,16,768]
    const float* abias = (const float*)d_in[1];   // [512,512,512]
    const float* Wq = (const float*)d_in[2];
    const float* bq = (const float*)d_in[3];
    const float* Wk = (const float*)d_in[4];
    const float* bk = (const float*)d_in[5];
    const float* Wv = (const float*)d_in[6];
    const float* bv = (const float*)d_in[7];
    const float* Wo = (const float*)d_in[8];
    const float* bo = (const float*)d_in[9];
    float* out = (float*)d_out;

    // workspace layout (floats): q | k | v | attn, each 512*512*24 or 8192*768
    float* ws = (float*)d_ws;
    const size_t QKV_ELEMS = (size_t)BATCH * HEADS * T_SEQ * HDIM; // 6291456
    float* qb = ws;
    float* kb = ws + QKV_ELEMS;
    float* vb = ws + 2 * QKV_ELEMS;
    float* ab = ws + 3 * QKV_ELEMS;                                // [8192,768]

    dim3 gA(ROWS / 64, 36);
    qkv_proj_kernel<<<gA, 256, 0, stream>>>(query, Wq, Wk, Wv, bq, bk, bv, qb, kb, vb);

    dim3 gB(BATCH * HEADS, T_SEQ / 16);
    attn_kernel<<<gB, 256, 0, stream>>>(qb, kb, vb, abias, ab);

    dim3 gC(ROWS / 64, EMB / 64);
    out_proj_kernel<<<gC, 256, 0, stream>>>(ab, Wo, bo, out);
}